// Round 15
// baseline (241.873 us; speedup 1.0000x reference)
//
#include <hip/hip_runtime.h>
#include <cfloat>
#include <climits>

// Retriever: cosine-sim top-5 over 100k knowledge vectors + gather.
// v15: split-K x3 sims. Each block owns a K-third (256) -> A-cache = 32 VGPR
// (vs 96), staging depth-2 ping-pong = 32 VGPR -> total ~105 -> 16 waves/CU
// (2x all prior rounds; tests the per-CU read-throughput theory).
// sims writes raw partial dots (coalesced 1KB/wave stores) + partial Gram
// norms; a streaming combine kernel sums thirds, applies rsqrt, does top-8.
// Then merge -> top-16 -> exact f32 rescore -> top-5 -> gather.

#define BQ 64
#define DD 768
#define NK 100000
#define LK 32
#define K_TOP 5
#define TROWS 16                    // ke rows per tile
#define NTIL (NK / TROWS)           // 6250
#define NBT 512                     // sims blocks per K-third
#define KTH 256                     // K elems per third
#define CTILES 50                   // tiles per combine block
#define NCB (NTIL / CTILES)         // 125 combine blocks
#define T_CAND 16                   // rescore candidate count

typedef __attribute__((ext_vector_type(8))) short short8;
typedef __attribute__((ext_vector_type(4))) float f32x4;

static __device__ __forceinline__ ushort bf16_rtn(float x) {
    uint u = __float_as_uint(x);
    return (ushort)((u + 0x7FFFu + ((u >> 16) & 1u)) >> 16);
}

#define INS8(v, n, va, ia)                                                  \
    _Pragma("unroll")                                                       \
    for (int m_ = 0; m_ < 8; ++m_) {                                        \
        if ((v) > va[m_]) {                                                 \
            float tv_ = va[m_]; va[m_] = (v); (v) = tv_;                    \
            int ti_ = ia[m_]; ia[m_] = (n); (n) = ti_;                      \
        }                                                                   \
    }

// ---------- phase 0: query -> normalized bf16 in FRAGMENT-MAJOR layout ----------
__global__ __launch_bounds__(256) void prep_kernel(const float* __restrict__ q,
                                                   ushort* __restrict__ qf,
                                                   float* __restrict__ qn) {
    const int b = blockIdx.x, t = threadIdx.x;
    __shared__ float red[4];
    float v[3];
    float s = 0.f;
#pragma unroll
    for (int i = 0; i < 3; ++i) {
        v[i] = q[b * DD + t + i * 256];
        s = fmaf(v[i], v[i], s);
    }
    for (int off = 32; off > 0; off >>= 1) s += __shfl_down(s, off, 64);
    if ((t & 63) == 0) red[t >> 6] = s;
    __syncthreads();
    const float tot = red[0] + red[1] + red[2] + red[3];
    const float rq = rsqrtf(tot);
    const int qb = b >> 4, bi = b & 15;
#pragma unroll
    for (int i = 0; i < 3; ++i) {
        const int k = t + i * 256;
        const int kt = k >> 5, lg = (k >> 3) & 3, j = k & 7;
        qf[((size_t)(kt * 4 + qb) * 64 + lg * 16 + bi) * 8 + j] = bf16_rtn(v[i] * rq);
    }
    if (t == 0) qn[b] = sqrtf(tot);
}

// ---------- phase 1: split-K sims, depth-2 staging, 16 waves/CU ----------
// Grid: 1536 = 3 thirds x 512. Block: 4 waves; wave w stages/owns q-group w.
// Per tile: convert ping-pong buf -> bf16 LDS (swizzled) -> barrier ->
// 8-step K-loop (VMEM-free) -> wave-private LDS transpose -> one coalesced
// 1KB store of partial dots -> barrier. Partial Gram norms from MFMA diag.
__global__ __launch_bounds__(256, 4) void sims_kernel(const ushort* __restrict__ qf,
                                                      const float* __restrict__ ke,
                                                      float* __restrict__ simsP,
                                                      float* __restrict__ simsN) {
    __shared__ ushort Bb[TROWS * KTH];   // 8192 B bf16, swizzled
    __shared__ float  Sw[4][256];        // wave-private store-transpose (4KB)

    const int t = threadIdx.x;
    const int w = t >> 6, l = t & 63;
    const int lg = l >> 4, li = l & 15;
    const int h = blockIdx.x / NBT;      // K-third
    const int b = blockIdx.x % NBT;

    f32x4 srA[4], srB[4];                // depth-2 ping-pong (16+16 VGPR)

#define ISSUE(SR, tl) do {                                                  \
        const float* g_ = ke + (size_t)((tl) * TROWS + w * 4) * DD          \
                          + h * KTH + l * 4;                                \
        _Pragma("unroll")                                                   \
        for (int i_ = 0; i_ < 4; ++i_)                                      \
            SR[i_] = *(const f32x4*)(g_ + i_ * DD);                         \
    } while (0)

#define PROCESS(SR, tl, nn) do {                                            \
        char* bb_ = (char*)Bb;                                              \
        _Pragma("unroll")                                                   \
        for (int i_ = 0; i_ < 4; ++i_) {                                    \
            const int row_ = w * 4 + i_;                                    \
            const int ad_ = (row_ * 512 + l * 8) ^ ((row_ & 7) << 4);       \
            uint2 u_;                                                       \
            u_.x = __builtin_amdgcn_perm(__float_as_uint(SR[i_][1]),        \
                                         __float_as_uint(SR[i_][0]),        \
                                         0x07060302u);                      \
            u_.y = __builtin_amdgcn_perm(__float_as_uint(SR[i_][3]),        \
                                         __float_as_uint(SR[i_][2]),        \
                                         0x07060302u);                      \
            *(uint2*)(bb_ + ad_) = u_;                                      \
        }                                                                   \
        if ((nn) < NTIL) ISSUE(SR, nn);                                     \
        asm volatile("s_waitcnt lgkmcnt(0)" ::: "memory");                  \
        __builtin_amdgcn_sched_barrier(0);                                  \
        __builtin_amdgcn_s_barrier();                                       \
        __builtin_amdgcn_sched_barrier(0);                                  \
        const int boff_ = li * 512 + lg * 16;                               \
        const int bsw_ = (li & 7) << 4;                                     \
        f32x4 acc_ = (f32x4){0.f, 0.f, 0.f, 0.f};                           \
        f32x4 ncc_ = (f32x4){0.f, 0.f, 0.f, 0.f};                           \
        short8 br_[2];                                                      \
        br_[0] = *(const short8*)(bb_ + (boff_ ^ bsw_));                    \
        _Pragma("unroll")                                                   \
        for (int s_ = 0; s_ < 8; ++s_) {                                    \
            const int cb_ = s_ & 1;                                         \
            if (s_ < 7)                                                     \
                br_[cb_ ^ 1] = *(const short8*)(bb_ +                       \
                                   ((boff_ + (s_ + 1) * 64) ^ bsw_));       \
            acc_ = __builtin_amdgcn_mfma_f32_16x16x32_bf16(                 \
                A[s_], br_[cb_], acc_, 0, 0, 0);                            \
            ncc_ = __builtin_amdgcn_mfma_f32_16x16x32_bf16(                 \
                br_[cb_], br_[cb_], ncc_, 0, 0, 0);                         \
        }                                                                   \
        _Pragma("unroll")                                                   \
        for (int r_ = 0; r_ < 4; ++r_)                                      \
            Sw[w][(lg * 4 + r_) * 16 + li] = acc_[r_];                      \
        float x_ = ncc_[li & 3];                                            \
        float dsq_ = __shfl(x_, ((li >> 2) << 4) | li, 64);                 \
        f32x4 so_ = *(const f32x4*)&Sw[w][l * 4];                           \
        *(f32x4*)(simsP + ((size_t)(h * NTIL + (tl)) * 64 + w * 16) * 16    \
                  + l * 4) = so_;                                           \
        if (w == 0 && l < 16)                                               \
            simsN[(size_t)(h * NTIL + (tl)) * 16 + l] = dsq_;               \
        asm volatile("s_waitcnt lgkmcnt(0)" ::: "memory");                  \
        __builtin_amdgcn_sched_barrier(0);                                  \
        __builtin_amdgcn_s_barrier();                                       \
        __builtin_amdgcn_sched_barrier(0);                                  \
    } while (0)

    // prologue: two bursts in flight, then A preload (8 frags = 32 VGPR)
    ISSUE(srA, b);
    ISSUE(srB, b + NBT);
    const ushort* aq = qf + (size_t)w * 512 + l * 8;
    short8 A[8];
#pragma unroll
    for (int s = 0; s < 8; ++s)
        A[s] = *(const short8*)(aq + (size_t)(h * 8 + s) * 2048);

    for (int k = 0; k < 12; k += 2) {
        PROCESS(srA, b + k * NBT, b + (k + 2) * NBT);
        PROCESS(srB, b + (k + 1) * NBT, b + (k + 3) * NBT);
    }
    if (b + 12 * NBT < NTIL) {
        PROCESS(srA, b + 12 * NBT, NTIL);
    }
#undef PROCESS
#undef ISSUE
}

// ---------- phase 2: combine thirds -> cosine -> per-block top-8 ----------
__global__ __launch_bounds__(256) void combine_kernel(const float* __restrict__ simsP,
                                                      const float* __restrict__ simsN,
                                                      float2* __restrict__ pv) {
    const int c = blockIdx.x, t = threadIdx.x;
    const int q = t >> 2, jq = t & 3;

    float v8[8]; int i8[8];
#pragma unroll
    for (int m = 0; m < 8; ++m) { v8[m] = -FLT_MAX; i8[m] = INT_MAX; }

    const float* P1 = simsP + (size_t)NTIL * 1024;
    const float* P2 = simsP + (size_t)2 * NTIL * 1024;
    const float* N1 = simsN + (size_t)NTIL * 16;
    const float* N2 = simsN + (size_t)2 * NTIL * 16;

    for (int tt = 0; tt < CTILES; ++tt) {
        const int tile = c * CTILES + tt;
        const size_t pb = (size_t)tile * 1024 + t * 4;
        f32x4 p0 = *(const f32x4*)(simsP + pb);
        f32x4 p1 = *(const f32x4*)(P1 + pb);
        f32x4 p2 = *(const f32x4*)(P2 + pb);
        const size_t nb_ = (size_t)tile * 16 + jq * 4;
        f32x4 n0 = *(const f32x4*)(simsN + nb_);
        f32x4 n1 = *(const f32x4*)(N1 + nb_);
        f32x4 n2 = *(const f32x4*)(N2 + nb_);
        const int nbase = tile * 16 + jq * 4;
#pragma unroll
        for (int j = 0; j < 4; ++j) {
            float s = (p0[j] + p1[j] + p2[j]) * rsqrtf(n0[j] + n1[j] + n2[j]);
            int n = nbase + j;
            if (s > v8[7]) { INS8(s, n, v8, i8); }
        }
    }

    __shared__ float sv[256][8];
    __shared__ int   si[256][8];
#pragma unroll
    for (int m = 0; m < 8; ++m) { sv[t][m] = v8[m]; si[t][m] = i8[m]; }
    __syncthreads();
    if (t < BQ) {
        float vf[8]; int nf[8];
#pragma unroll
        for (int m = 0; m < 8; ++m) { vf[m] = -FLT_MAX; nf[m] = INT_MAX; }
        for (int s = 0; s < 4; ++s) {
            const int row = t * 4 + s;
#pragma unroll
            for (int m = 0; m < 8; ++m) {
                float v = sv[row][m]; int n = si[row][m];
                INS8(v, n, vf, nf);
            }
        }
        float2* dst = pv + ((size_t)t * NCB + c) * 8;
#pragma unroll
        for (int m = 0; m < 8; ++m) dst[m] = make_float2(vf[m], __int_as_float(nf[m]));
    }
}

// ---------- phase 3: merge 125x8 -> top-16 -> exact f32 rescore -> top-5 -> gather ----------
__global__ __launch_bounds__(256) void merge_rescore_kernel(
    const float2* __restrict__ pv,
    const float* __restrict__ q, const float* __restrict__ ke,
    const int* __restrict__ kf, const float* __restrict__ qn,
    float* __restrict__ out) {
    const int qi = blockIdx.x, t = threadIdx.x;
    __shared__ float sv[256][8];
    __shared__ int   si[256][8];
    __shared__ int   ci[T_CAND];
    __shared__ float cs_[T_CAND];
    __shared__ int   fi[K_TOP];

    float v8[8]; int i8[8];
#pragma unroll
    for (int m = 0; m < 8; ++m) { v8[m] = -FLT_MAX; i8[m] = INT_MAX; }

    // coalesced scan of this query's partials [NCB*8 = 1000]
    const float2* src = pv + (size_t)qi * NCB * 8;
    for (int c = t; c < NCB * 8; c += 256) {
        float2 e = src[c];
        float v = e.x; int n = __float_as_int(e.y);
        INS8(v, n, v8, i8);
    }
#pragma unroll
    for (int m = 0; m < 8; ++m) { sv[t][m] = v8[m]; si[t][m] = i8[m]; }
    __syncthreads();

    for (int active = 64; active >= 4; active >>= 2) {
        if (t < active) {
#pragma unroll
            for (int m = 0; m < 8; ++m) { v8[m] = -FLT_MAX; i8[m] = INT_MAX; }
            for (int s = 0; s < 4; ++s) {
                int row = t * 4 + s;
#pragma unroll
                for (int m = 0; m < 8; ++m) {
                    float v = sv[row][m]; int n = si[row][m];
                    INS8(v, n, v8, i8);
                }
            }
        }
        __syncthreads();
        if (t < active) {
#pragma unroll
            for (int m = 0; m < 8; ++m) { sv[t][m] = v8[m]; si[t][m] = i8[m]; }
        }
        __syncthreads();
    }

    if (t == 0) {
        float v16[T_CAND]; int i16[T_CAND];
#pragma unroll
        for (int m = 0; m < T_CAND; ++m) { v16[m] = -FLT_MAX; i16[m] = INT_MAX; }
        for (int row = 0; row < 4; ++row) {
#pragma unroll
            for (int m = 0; m < 8; ++m) {
                float v = sv[row][m]; int n = si[row][m];
#pragma unroll
                for (int p = 0; p < T_CAND; ++p) {
                    if (v > v16[p]) {
                        float tv = v16[p]; v16[p] = v; v = tv;
                        int ti = i16[p]; i16[p] = n; n = ti;
                    }
                }
            }
        }
#pragma unroll
        for (int m = 0; m < T_CAND; ++m) ci[m] = i16[m];
    }
    __syncthreads();

    // exact f32 rescore; wave w -> candidates w*4..w*4+3
    {
        const int w = t >> 6, lane = t & 63;
        for (int cc = 0; cc < 4; ++cc) {
            int c = w * 4 + cc;
            int row = ci[c];
            const float* kp = ke + (size_t)row * DD + lane * 12;
            const float* qp = q + qi * DD + lane * 12;
            float d = 0.f, ks = 0.f;
#pragma unroll
            for (int i = 0; i < 12; ++i) {
                float kv = kp[i];
                d = fmaf(qp[i], kv, d);
                ks = fmaf(kv, kv, ks);
            }
#pragma unroll
            for (int off = 32; off > 0; off >>= 1) {
                d += __shfl_xor(d, off, 64);
                ks += __shfl_xor(ks, off, 64);
            }
            if (lane == 0)
                cs_[c] = d / fmaxf(qn[qi] * sqrtf(ks), 1e-8f);
        }
    }
    __syncthreads();

    // final top-5 of 16 (tie -> lower index)
    if (t == 0) {
        float v5[K_TOP]; int i5[K_TOP];
#pragma unroll
        for (int m = 0; m < K_TOP; ++m) { v5[m] = -FLT_MAX; i5[m] = INT_MAX; }
        for (int c = 0; c < T_CAND; ++c) {
            float v = cs_[c]; int n = ci[c];
#pragma unroll
            for (int m = 0; m < K_TOP; ++m) {
                bool take = (v > v5[m]) || (v == v5[m] && n < i5[m]);
                if (take) {
                    float tv = v5[m]; v5[m] = v; v = tv;
                    int ti = i5[m]; i5[m] = n; n = ti;
                }
            }
        }
#pragma unroll
        for (int m = 0; m < K_TOP; ++m) fi[m] = i5[m];
    }
    __syncthreads();

    // gather knowledge_full rows (ints < 30000 exact in f32)
    for (int pos = t; pos < K_TOP * LK; pos += 256) {
        int m = pos >> 5, lgi = pos & 31;
        out[(qi * K_TOP + m) * LK + lgi] = (float)kf[(size_t)fi[m] * LK + lgi];
    }
    // gather embed rows
    const int EO = BQ * K_TOP * LK;  // 10240
    for (int m = 0; m < K_TOP; ++m) {
        const float4* srcp = (const float4*)(ke + (size_t)fi[m] * DD);
        float4* dstp = (float4*)(out + EO + (size_t)(qi * K_TOP + m) * DD);
        for (int pos = t; pos < DD / 4; pos += 256) dstp[pos] = srcp[pos];
    }
}

extern "C" void kernel_launch(void* const* d_in, const int* in_sizes, int n_in,
                              void* d_out, int out_size, void* d_ws, size_t ws_size,
                              hipStream_t stream) {
    const float* query = (const float*)d_in[0];
    const float* ke    = (const float*)d_in[1];
    const int*   kf    = (const int*)d_in[2];
    float* out = (float*)d_out;

    // ws: simsP 3*6250*1024 f32 (76.8MB) | simsN 3*6250*16 f32 | pv 64*125*8 f2 | qf | qn
    float*  simsP = (float*)d_ws;
    float*  simsN = simsP + (size_t)3 * NTIL * 1024;
    float2* pv    = (float2*)(simsN + (size_t)3 * NTIL * 16);
    ushort* qf    = (ushort*)((char*)pv + (size_t)BQ * NCB * 8 * sizeof(float2));
    float*  qn    = (float*)((char*)qf + (size_t)24 * 4 * 64 * 8 * sizeof(ushort));

    prep_kernel<<<BQ, 256, 0, stream>>>(query, qf, qn);
    sims_kernel<<<3 * NBT, 256, 0, stream>>>(qf, ke, simsP, simsN);
    combine_kernel<<<NCB, 256, 0, stream>>>(simsP, simsN, pv);
    merge_rescore_kernel<<<BQ, 256, 0, stream>>>(pv, query, ke, kf, qn, out);
}

// Round 16
// 144.666 us; speedup vs baseline: 1.6719x; 1.6719x over previous
//
#include <hip/hip_runtime.h>
#include <cfloat>
#include <climits>

// Retriever: cosine-sim top-5 over 100k knowledge vectors + gather.
// v16 = v12 (best, 145.5us) with the per-tile phase structure thinned:
// (1) double-buffered Bb -> ONE barrier per tile (write/read phases of the
//     two buffers provably separated by the single barrier),
// (2) wave-private S slice + intra-wave scan (no cross-wave S round-trip),
// (3) guarded top-8 insert (1 cmp in the common miss case).
// Staging, K-loop, Gram-MFMA norms, A-preload, merge: identical to v12.

#define BQ 64
#define DD 768
#define NK 100000
#define LK 32
#define K_TOP 5
#define TROWS 16                    // ke rows per tile
#define NTIL (NK / TROWS)           // 6250 (exact)
#define NBLKS 512                   // persistent sims blocks (2/CU)
#define T_CAND 16                   // rescore candidate count

typedef __attribute__((ext_vector_type(8))) short short8;
typedef __attribute__((ext_vector_type(4))) float f32x4;

static __device__ __forceinline__ ushort bf16_rtn(float x) {
    uint u = __float_as_uint(x);
    return (ushort)((u + 0x7FFFu + ((u >> 16) & 1u)) >> 16);
}

#define INS8(v, n, va, ia)                                                  \
    _Pragma("unroll")                                                       \
    for (int m_ = 0; m_ < 8; ++m_) {                                        \
        if ((v) > va[m_]) {                                                 \
            float tv_ = va[m_]; va[m_] = (v); (v) = tv_;                    \
            int ti_ = ia[m_]; ia[m_] = (n); (n) = ti_;                      \
        }                                                                   \
    }

// ---------- phase 0: query -> normalized bf16 in FRAGMENT-MAJOR layout ----------
// qf[((kt*4 + (b>>4))*64 + lg*16 + (b&15))*8 + j] = bf16(q[b][kt*32+lg*8+j] * rq)
__global__ __launch_bounds__(256) void prep_kernel(const float* __restrict__ q,
                                                   ushort* __restrict__ qf,
                                                   float* __restrict__ qn) {
    const int b = blockIdx.x, t = threadIdx.x;
    __shared__ float red[4];
    float v[3];
    float s = 0.f;
#pragma unroll
    for (int i = 0; i < 3; ++i) {
        v[i] = q[b * DD + t + i * 256];
        s = fmaf(v[i], v[i], s);
    }
    for (int off = 32; off > 0; off >>= 1) s += __shfl_down(s, off, 64);
    if ((t & 63) == 0) red[t >> 6] = s;
    __syncthreads();
    const float tot = red[0] + red[1] + red[2] + red[3];
    const float rq = rsqrtf(tot);
    const int qb = b >> 4, bi = b & 15;
#pragma unroll
    for (int i = 0; i < 3; ++i) {
        const int k = t + i * 256;
        const int kt = k >> 5, lg = (k >> 3) & 3, j = k & 7;
        qf[((size_t)(kt * 4 + qb) * 64 + lg * 16 + bi) * 8 + j] = bf16_rtn(v[i] * rq);
    }
    if (t == 0) qn[b] = sqrtf(tot);
}

// ---------- phase 1: persistent sims, 1 barrier/tile, wave-private scan ----------
__global__ __launch_bounds__(256, 2) void sims_kernel(const ushort* __restrict__ qf,
                                                      const float* __restrict__ ke,
                                                      float2* __restrict__ pv) {
    __shared__ ushort Bb[2][TROWS * DD];   // 2 x 24576 B, swizzled bf16
    __shared__ float  Sw[4][16][17];       // wave-private S slices (4.25KB)

    const int t = threadIdx.x;
    const int w = t >> 6, l = t & 63;
    const int lg = l >> 4, li = l & 15;
    const int sq = l & 15, sj = l >> 4;    // scan: query-in-wave + col quarter

    float v8[8]; int i8[8];
#pragma unroll
    for (int m = 0; m < 8; ++m) { v8[m] = -FLT_MAX; i8[m] = INT_MAX; }

    f32x4 sr[4][3];                        // depth-1 reg staging (v12-proven)
    const int b = blockIdx.x;

    // prologue: tile-0 stage first (oldest in vmcnt queue), then A preload
    {
        const float* g = ke + (size_t)(b * TROWS + w * 4) * DD + l * 4;
#pragma unroll
        for (int i = 0; i < 4; ++i)
#pragma unroll
            for (int c = 0; c < 3; ++c)
                sr[i][c] = *(const f32x4*)(g + i * DD + c * 256);
    }
    const ushort* aq = qf + (size_t)w * 512 + l * 8;
    short8 A[24];
#pragma unroll
    for (int p = 0; p < 24; ++p) A[p] = *(const short8*)(aq + p * 2048);

    for (int k = 0; k < 13; ++k) {
        const int tile = b + k * NBLKS;
        if (tile >= NTIL) break;
        const int nxt = tile + NBLKS;

        // ---- convert own 4 rows -> trunc bf16 -> Bb[k&1] (swizzled) ----
        char* bb = (char*)(&Bb[k & 1][0]);
#pragma unroll
        for (int i = 0; i < 4; ++i) {
            const int row = w * 4 + i;
            const int base = row * 1536 + l * 8;
            const int sw = (row & 7) << 4;
#pragma unroll
            for (int c = 0; c < 3; ++c) {
                uint2 u;
                u.x = __builtin_amdgcn_perm(__float_as_uint(sr[i][c][1]),
                                            __float_as_uint(sr[i][c][0]),
                                            0x07060302u);
                u.y = __builtin_amdgcn_perm(__float_as_uint(sr[i][c][3]),
                                            __float_as_uint(sr[i][c][2]),
                                            0x07060302u);
                *(uint2*)(bb + ((base + c * 512) ^ sw)) = u;
            }
        }
        // ---- issue next tile's stage loads (fly under K-loop + scan) ----
        if (nxt < NTIL) {
            const float* g = ke + (size_t)(nxt * TROWS + w * 4) * DD + l * 4;
#pragma unroll
            for (int i = 0; i < 4; ++i)
#pragma unroll
                for (int c = 0; c < 3; ++c)
                    sr[i][c] = *(const f32x4*)(g + i * DD + c * 256);
        }
        asm volatile("s_waitcnt lgkmcnt(0)" ::: "memory");
        __builtin_amdgcn_sched_barrier(0);
        __builtin_amdgcn_s_barrier();      // the ONLY barrier per tile
        __builtin_amdgcn_sched_barrier(0);

        // ---- K-loop: pure LDS + registers (zero VMEM) ----
        const int boff = li * 1536 + lg * 16;
        const int bsw = (li & 7) << 4;
        f32x4 acc = (f32x4){0.f, 0.f, 0.f, 0.f};
        f32x4 ncc = (f32x4){0.f, 0.f, 0.f, 0.f};
        short8 br[2];
        br[0] = *(const short8*)(bb + (boff ^ bsw));
#pragma unroll
        for (int kt = 0; kt < 24; ++kt) {
            const int cb = kt & 1;
            if (kt < 23)
                br[cb ^ 1] = *(const short8*)(bb + ((boff + (kt + 1) * 64) ^ bsw));
            acc = __builtin_amdgcn_mfma_f32_16x16x32_bf16(A[kt], br[cb], acc, 0, 0, 0);
            ncc = __builtin_amdgcn_mfma_f32_16x16x32_bf16(br[cb], br[cb], ncc, 0, 0, 0);
        }

        // ---- row norm from Gram diag: C[i][i] at lane ((i>>2)<<4)|i, reg i&3 ----
        float x = ncc[li & 3];
        float dsq = __shfl(x, ((li >> 2) << 4) | li, 64);
        float rk = rsqrtf(dsq);

        // ---- wave-private S (C layout: col=li, q-row=lg*4+r), no barrier ----
#pragma unroll
        for (int r = 0; r < 4; ++r) Sw[w][lg * 4 + r][li] = acc[r] * rk;
        asm volatile("s_waitcnt lgkmcnt(0)" ::: "memory");
        __builtin_amdgcn_sched_barrier(0);

        // ---- intra-wave scan: lane l = (query sq of wave w, col quarter sj) ----
        {
            const int nb = tile * TROWS + sj * 4;
#pragma unroll
            for (int j = 0; j < 4; ++j) {
                float v = Sw[w][sq][sj * 4 + j];
                if (v > v8[7]) { int n = nb + j; INS8(v, n, v8, i8); }
            }
        }
    }

    // ---- final merge: query q's 4 quarter-lists live at wave q>>4,
    //      lanes (q&15)+16s; merge via LDS (reuse Bb[0], 16KB) ----
    __syncthreads();
    float2* mg = (float2*)(&Bb[0][0]);
#pragma unroll
    for (int m = 0; m < 8; ++m) mg[t * 8 + m] = make_float2(v8[m], __int_as_float(i8[m]));
    __syncthreads();
    if (t < BQ) {
        float vf[8]; int nf[8];
#pragma unroll
        for (int m = 0; m < 8; ++m) { vf[m] = -FLT_MAX; nf[m] = INT_MAX; }
        const int wq = t >> 4, iq = t & 15;
        for (int s = 0; s < 4; ++s) {
            const float2* rowp = &mg[(wq * 64 + iq + 16 * s) * 8];
#pragma unroll
            for (int m = 0; m < 8; ++m) {
                float v = rowp[m].x; int n = __float_as_int(rowp[m].y);
                INS8(v, n, vf, nf);
            }
        }
        float2* dst = pv + ((size_t)t * NBLKS + blockIdx.x) * 8;
#pragma unroll
        for (int m = 0; m < 8; ++m) dst[m] = make_float2(vf[m], __int_as_float(nf[m]));
    }
}

// ---------- phase 2: merge 512x8 -> top-16 -> exact f32 rescore -> top-5 -> gather ----------
__global__ __launch_bounds__(256) void merge_rescore_kernel(
    const float2* __restrict__ pv,
    const float* __restrict__ q, const float* __restrict__ ke,
    const int* __restrict__ kf, const float* __restrict__ qn,
    float* __restrict__ out) {
    const int qi = blockIdx.x, t = threadIdx.x;
    __shared__ float sv[256][8];
    __shared__ int   si[256][8];
    __shared__ int   ci[T_CAND];
    __shared__ float cs_[T_CAND];
    __shared__ int   fi[K_TOP];

    float v8[8]; int i8[8];
#pragma unroll
    for (int m = 0; m < 8; ++m) { v8[m] = -FLT_MAX; i8[m] = INT_MAX; }

    // coalesced scan of this query's partials [NBLKS*8 = 4096]
    const float2* src = pv + (size_t)qi * NBLKS * 8;
#pragma unroll 4
    for (int c = t; c < NBLKS * 8; c += 256) {
        float2 e = src[c];
        float v = e.x; int n = __float_as_int(e.y);
        if (v > v8[7]) { INS8(v, n, v8, i8); }
    }
#pragma unroll
    for (int m = 0; m < 8; ++m) { sv[t][m] = v8[m]; si[t][m] = i8[m]; }
    __syncthreads();

    // tree merge 256 -> 64 -> 16 -> 4 rows (top-8 each; global rank<=8 survives)
    for (int active = 64; active >= 4; active >>= 2) {
        if (t < active) {
#pragma unroll
            for (int m = 0; m < 8; ++m) { v8[m] = -FLT_MAX; i8[m] = INT_MAX; }
            for (int s = 0; s < 4; ++s) {
                int row = t * 4 + s;
#pragma unroll
                for (int m = 0; m < 8; ++m) {
                    float v = sv[row][m]; int n = si[row][m];
                    INS8(v, n, v8, i8);
                }
            }
        }
        __syncthreads();
        if (t < active) {
#pragma unroll
            for (int m = 0; m < 8; ++m) { sv[t][m] = v8[m]; si[t][m] = i8[m]; }
        }
        __syncthreads();
    }

    // thread 0: 4 rows x 8 -> top-16
    if (t == 0) {
        float v16[T_CAND]; int i16[T_CAND];
#pragma unroll
        for (int m = 0; m < T_CAND; ++m) { v16[m] = -FLT_MAX; i16[m] = INT_MAX; }
        for (int row = 0; row < 4; ++row) {
#pragma unroll
            for (int m = 0; m < 8; ++m) {
                float v = sv[row][m]; int n = si[row][m];
#pragma unroll
                for (int p = 0; p < T_CAND; ++p) {
                    if (v > v16[p]) {
                        float tv = v16[p]; v16[p] = v; v = tv;
                        int ti = i16[p]; i16[p] = n; n = ti;
                    }
                }
            }
        }
#pragma unroll
        for (int m = 0; m < T_CAND; ++m) ci[m] = i16[m];
    }
    __syncthreads();

    // exact f32 rescore; wave w -> candidates w*4..w*4+3
    {
        const int w = t >> 6, lane = t & 63;
        for (int cc = 0; cc < 4; ++cc) {
            int c = w * 4 + cc;
            int row = ci[c];
            const float* kp = ke + (size_t)row * DD + lane * 12;
            const float* qp = q + qi * DD + lane * 12;
            float d = 0.f, ks = 0.f;
#pragma unroll
            for (int i = 0; i < 12; ++i) {
                float kv = kp[i];
                d = fmaf(qp[i], kv, d);
                ks = fmaf(kv, kv, ks);
            }
#pragma unroll
            for (int off = 32; off > 0; off >>= 1) {
                d += __shfl_xor(d, off, 64);
                ks += __shfl_xor(ks, off, 64);
            }
            if (lane == 0)
                cs_[c] = d / fmaxf(qn[qi] * sqrtf(ks), 1e-8f);
        }
    }
    __syncthreads();

    // final top-5 of 16 (tie -> lower index)
    if (t == 0) {
        float v5[K_TOP]; int i5[K_TOP];
#pragma unroll
        for (int m = 0; m < K_TOP; ++m) { v5[m] = -FLT_MAX; i5[m] = INT_MAX; }
        for (int c = 0; c < T_CAND; ++c) {
            float v = cs_[c]; int n = ci[c];
#pragma unroll
            for (int m = 0; m < K_TOP; ++m) {
                bool take = (v > v5[m]) || (v == v5[m] && n < i5[m]);
                if (take) {
                    float tv = v5[m]; v5[m] = v; v = tv;
                    int ti = i5[m]; i5[m] = n; n = ti;
                }
            }
        }
#pragma unroll
        for (int m = 0; m < K_TOP; ++m) fi[m] = i5[m];
    }
    __syncthreads();

    // gather knowledge_full rows (ints < 30000 exact in f32)
    for (int pos = t; pos < K_TOP * LK; pos += 256) {
        int m = pos >> 5, lgi = pos & 31;
        out[(qi * K_TOP + m) * LK + lgi] = (float)kf[(size_t)fi[m] * LK + lgi];
    }
    // gather embed rows
    const int EO = BQ * K_TOP * LK;  // 10240
    for (int m = 0; m < K_TOP; ++m) {
        const float4* srcp = (const float4*)(ke + (size_t)fi[m] * DD);
        float4* dstp = (float4*)(out + EO + (size_t)(qi * K_TOP + m) * DD);
        for (int pos = t; pos < DD / 4; pos += 256) dstp[pos] = srcp[pos];
    }
}

extern "C" void kernel_launch(void* const* d_in, const int* in_sizes, int n_in,
                              void* d_out, int out_size, void* d_ws, size_t ws_size,
                              hipStream_t stream) {
    const float* query = (const float*)d_in[0];
    const float* ke    = (const float*)d_in[1];
    const int*   kf    = (const int*)d_in[2];
    float* out = (float*)d_out;

    // ws layout: pv [64][512][8] float2 (2.1 MB) | qf [24*4*64*8] ushort | qn[64]
    float2* pv = (float2*)d_ws;
    ushort* qf = (ushort*)((char*)d_ws + (size_t)BQ * NBLKS * 8 * sizeof(float2));
    float*  qn = (float*)((char*)qf + (size_t)24 * 4 * 64 * 8 * sizeof(ushort));

    prep_kernel<<<BQ, 256, 0, stream>>>(query, qf, qn);
    sims_kernel<<<NBLKS, 256, 0, stream>>>(qf, ke, pv);
    merge_rescore_kernel<<<BQ, 256, 0, stream>>>(pv, query, ke, kf, qn, out);
}